// Round 17
// baseline (148.264 us; speedup 1.0000x reference)
//
#include <hip/hip_runtime.h>

#define SEQ   1024
#define HEADS 12
#define CDIM  768
#define BATCH 8

// 0.125 * log2(e): folds the 1/sqrt(64) score scale and the exp->exp2 change
#define QSCALE 0.18033688011112042f

typedef __attribute__((ext_vector_type(8))) short bf16x8;
typedef __attribute__((ext_vector_type(4))) float f32x4;
typedef __attribute__((ext_vector_type(16))) float f32x16;
typedef __attribute__((ext_vector_type(4))) float float4v;
typedef __attribute__((ext_vector_type(4))) short short4v;

__device__ __forceinline__ void gload_lds16(const void* g, void* l) {
  __builtin_amdgcn_global_load_lds(
      (const __attribute__((address_space(1))) unsigned int*)g,
      (__attribute__((address_space(3))) unsigned int*)l, 16, 0, 0);
}

__device__ __forceinline__ unsigned short f2bf(float f) {
  union { float f; unsigned u; } v; v.f = f;
  unsigned r = v.u + 0x7fff + ((v.u >> 16) & 1);
  return (unsigned short)(r >> 16);
}

// pack two f32 -> u32 of 2x bf16 (lo = a, hi = b); no builtin on gfx950
__device__ __forceinline__ unsigned cvtpk(float a, float b) {
  unsigned r;
  asm("v_cvt_pk_bf16_f32 %0, %1, %2" : "=v"(r) : "v"(a), "v"(b));
  return r;
}

// select bf16 half of a packed u32 as f32 (odd -> high half, even -> low)
__device__ __forceinline__ float bfsel(unsigned u, int odd) {
  union { unsigned u; float f; } v;
  v.u = odd ? (u & 0xffff0000u) : (u << 16);
  return v.f;
}

// Merged prep (single launch):
//   blocks [0,6144)      : x -> bf16
//   blocks [6144,6576)   : W_qkv transpose -> bf16
//   blocks [6576,6720)   : W_proj transpose -> bf16
//   blocks [6720,12864)  : pos -> posb bf16 (QSCALE folded, attn lane order)
__global__ __launch_bounds__(256) void prep_all_kernel(
    const float* __restrict__ x, short* __restrict__ A,
    const float* __restrict__ Wqkv, short* __restrict__ Bt,
    const float* __restrict__ Wproj, short* __restrict__ wpt,
    const float* __restrict__ P, short* __restrict__ PB) {
  __shared__ float tile[64][65];
  const int bid = blockIdx.x;
  const int t = threadIdx.x;
  if (bid < 6144) {
    int i = bid * 256 + t;
    int r = i / 192;
    int c4 = (i % 192) * 4;
    float4v xv = *(const float4v*)(x + (size_t)r * 768 + c4);
    short4v hi;
#pragma unroll
    for (int j = 0; j < 4; ++j) hi[j] = (short)f2bf(xv[j]);
    *(short4v*)(A + (size_t)r * 768 + c4) = hi;
  } else if (bid < 6576) {
    int idx = bid - 6144;
    int k0 = (idx % 12) * 64;
    int n0 = (idx / 12) * 64;
#pragma unroll
    for (int it = 0; it < 16; ++it) {
      int r = it * 4 + (t >> 6);
      int c = t & 63;
      tile[r][c] = Wqkv[(size_t)(k0 + r) * 2304 + n0 + c];
    }
    __syncthreads();
#pragma unroll
    for (int it = 0; it < 16; ++it) {
      int nr = it * 4 + (t >> 6);
      int kc = t & 63;
      Bt[(size_t)(n0 + nr) * 768 + k0 + kc] = (short)f2bf(tile[kc][nr]);
    }
  } else if (bid < 6720) {
    int idx = bid - 6576;
    int k0 = (idx % 12) * 64;
    int n0 = (idx / 12) * 64;
#pragma unroll
    for (int it = 0; it < 16; ++it) {
      int r = it * 4 + (t >> 6);
      int c = t & 63;
      tile[r][c] = Wproj[(size_t)(k0 + r) * 768 + n0 + c];
    }
    __syncthreads();
#pragma unroll
    for (int it = 0; it < 16; ++it) {
      int nr = it * 4 + (t >> 6);
      int kc = t & 63;
      wpt[(size_t)(n0 + nr) * 768 + k0 + kc] = (short)f2bf(tile[kc][nr]);
    }
  } else {
    int j = (bid - 6720) * 256 + t;   // 0..1572863
    int ln = j & 63, jh = (j >> 6) & 1, i0 = (j >> 7) & 1, w4 = (j >> 8) & 3,
        ti = (j >> 10) & 15, qb = (j >> 14) & 7, hh = j >> 17;
    int q = qb * 128 + w4 * 32 + (ln & 31);
    const float* src = P + ((size_t)hh * SEQ + q) * SEQ + ti * 64 + i0 * 32
                       + 4 * (ln >> 5) + 16 * jh;
    float4v v0 = *(const float4v*)(src);       // jl = 0..3
    float4v v1 = *(const float4v*)(src + 8);   // jl = 4..7
    union { short s[8]; bf16x8 v; } o;
#pragma unroll
    for (int p = 0; p < 4; ++p) {
      o.s[p]     = (short)f2bf(v0[p] * QSCALE);
      o.s[4 + p] = (short)f2bf(v1[p] * QSCALE);
    }
    *(bf16x8*)(PB + (size_t)j * 8) = o.v;
  }
}

// Shared 128x128-tile GEMM, BK=64, K=768, 8 waves (2x4), 16x16x32 bf16 MFMA.
// 2-phase issue-early pipeline; XCD-chunked linear grid.
// MODE 1: qkv (N=2304, 18 n-blocks); MODE 2: proj (N=768, 6 n-blocks).
template <int MODE>
__global__ __launch_bounds__(512, 4) void gemm_kernel(
    const short* __restrict__ A, const short* __restrict__ Bt,
    const float* __restrict__ bias,
    short* __restrict__ outQ, short* __restrict__ outK, short* __restrict__ outVT,
    float* __restrict__ outF) {
  constexpr int NBLK = (MODE == 1) ? 18 : 6;     // n-blocks per m-row
  constexpr int CHUNK = (MODE == 1) ? 144 : 48;  // nwg/8 (both divisible)
  const int bid = blockIdx.x;
  const int lb = (bid & 7) * CHUNK + (bid >> 3); // XCD-chunked, bijective
  const int n0 = (lb % NBLK) * 128;
  const int m0 = (lb / NBLK) * 128;

  __shared__ short Als[2][128 * 64];
  __shared__ short Bls[2][128 * 64];
  const int tid = threadIdx.x;
  const int lane = tid & 63;
  const int w = tid >> 6;
  const int wr = (w & 1) * 64;       // 2 row-groups of 64
  const int wc = (w >> 1) * 32;      // 4 col-groups of 32
  f32x4 acc[4][2];
#pragma unroll
  for (int mi = 0; mi < 4; ++mi)
#pragma unroll
    for (int ni = 0; ni < 2; ++ni) acc[mi][ni] = (f32x4){0.f, 0.f, 0.f, 0.f};

  auto STAGE = [&](int buf, int k0) {
#pragma unroll
    for (int pass = 0; pass < 2; ++pass) {
      int rbase = pass * 64 + w * 8;
      int row = rbase + (lane >> 3);
      int ul = (lane & 7) ^ (row & 7);
      gload_lds16(A + (size_t)(m0 + row) * 768 + k0 + ul * 8, Als[buf] + rbase * 64);
      gload_lds16(Bt + (size_t)(n0 + row) * 768 + k0 + ul * 8, Bls[buf] + rbase * 64);
    }
  };

  STAGE(0, 0);
  asm volatile("s_waitcnt vmcnt(0)" ::: "memory");
  __builtin_amdgcn_sched_barrier(0);
  __builtin_amdgcn_s_barrier();

  for (int t = 0; t < 12; ++t) {
    if (t < 11) STAGE((t + 1) & 1, (t + 1) * 64);   // loads fly during compute
    const short* Ab = Als[t & 1];
    const short* Bb = Bls[t & 1];
    __builtin_amdgcn_s_setprio(1);
#pragma unroll
    for (int kk = 0; kk < 2; ++kk) {
      bf16x8 af[4], bfv[2];
#pragma unroll
      for (int mi = 0; mi < 4; ++mi) {
        int row = wr + mi * 16 + (lane & 15);
        int off = (row * 128 + kk * 64 + (lane >> 4) * 16) ^ ((row & 7) << 4);
        af[mi] = *(const bf16x8*)((const char*)Ab + off);
      }
#pragma unroll
      for (int ni = 0; ni < 2; ++ni) {
        int row = wc + ni * 16 + (lane & 15);
        int off = (row * 128 + kk * 64 + (lane >> 4) * 16) ^ ((row & 7) << 4);
        bfv[ni] = *(const bf16x8*)((const char*)Bb + off);
      }
#pragma unroll
      for (int mi = 0; mi < 4; ++mi)
#pragma unroll
        for (int ni = 0; ni < 2; ++ni)
          acc[mi][ni] = __builtin_amdgcn_mfma_f32_16x16x32_bf16(
              af[mi], bfv[ni], acc[mi][ni], 0, 0, 0);
    }
    __builtin_amdgcn_s_setprio(0);
    if (t < 11) {
      // own stage(t+1) proven landed before the publishing barrier
      asm volatile("s_waitcnt vmcnt(0)" ::: "memory");
      __builtin_amdgcn_sched_barrier(0);
      __builtin_amdgcn_s_barrier();
    }
  }

  if (MODE == 1) {
    // block-uniform third: n0 multiple of 128, 128 | 768
    const int three = n0 / 768;
    const int nb = n0 - three * 768;
#pragma unroll
    for (int mi = 0; mi < 4; ++mi)
#pragma unroll
      for (int ni = 0; ni < 2; ++ni)
#pragma unroll
        for (int j = 0; j < 4; ++j) {
          int row = m0 + wr + mi * 16 + ((lane >> 4) << 2) + j;
          int col = n0 + wc + ni * 16 + (lane & 15);
          float v = acc[mi][ni][j] + bias[col];
          int rem = nb + wc + ni * 16 + (lane & 15);
          int hh = rem >> 6, d = rem & 63;
          int b = row >> 10, n = row & 1023;
          size_t bh = (size_t)(b * 12 + hh);
          if (three == 0)      outQ[(bh * 1024 + n) * 64 + d] = (short)f2bf(v * QSCALE);
          else if (three == 1) outK[(bh * 1024 + n) * 64 + d] = (short)f2bf(v);
          else                 outVT[(bh * 64 + d) * 1024 + n] = (short)f2bf(v);
        }
  } else {
#pragma unroll
    for (int mi = 0; mi < 4; ++mi)
#pragma unroll
      for (int ni = 0; ni < 2; ++ni)
#pragma unroll
        for (int j = 0; j < 4; ++j) {
          int row = m0 + wr + mi * 16 + ((lane >> 4) << 2) + j;
          int col = n0 + wc + ni * 16 + (lane & 15);
          outF[(size_t)row * 768 + col] = acc[mi][ni][j] + bias[col];
        }
  }
}

// build one PV B-frag (4 u32 = 8 bf16, k = kv) from packed P pairs:
// permlane32_swap(x=pk[m][p], y=pk[m+1][p]) -> x' = frag reg (own|swap),
// y' = frag reg (swap|own) for the two lane halves. 4 swaps per 32-kv block.
#define MKFRAG(B, pA, pB, pC, pD)                                    \
  { unsigned x0 = (pA), y0 = (pC), x1 = (pB), y1 = (pD);             \
    asm("v_permlane32_swap_b32 %0, %1" : "+v"(x0), "+v"(y0));        \
    asm("v_permlane32_swap_b32 %0, %1" : "+v"(x1), "+v"(y1));        \
    B.u[0] = x0; B.u[1] = x1; B.u[2] = y0; B.u[3] = y1; }

// Flash attention, 32x32x16 MFMA, swapped QK^T, fixed-shift softmax,
// permlane32_swap P-redistribute, distance-2 KV pipeline, coalesced
// pre-swizzled bf16 pos (QSCALE folded) prefetched at distance 1,
// h-major XCD swizzle. grid: 768 blocks x 256 threads; 4 waves x 32 q-rows.
__global__ __launch_bounds__(256, 3) void attn_kernel(
    const short* __restrict__ qb, const short* __restrict__ kb,
    const short* __restrict__ vtb, const short* __restrict__ posb,
    short* __restrict__ outb) {
  // h-major XCD swizzle: the 8 same-(h,qblk) diff-b blocks share one XCD L2.
  const int bid = blockIdx.x;
  const int lb = (bid & 7) * 96 + (bid >> 3);
  const int qblk = lb & 7;
  const int hb = lb >> 3;            // 0..95 = h*8 + b
  const int h = hb >> 3, b = hb & 7;

  const int tid = threadIdx.x, lane = tid & 63, w = tid >> 6;
  const int c5 = lane & 31, g1 = lane >> 5;
  const size_t bh = (size_t)(b * 12 + h);
  const short* Q = qb + bh * SEQ * 64;
  const short* K = kb + bh * SEQ * 64;
  const short* VT = vtb + bh * 64 * SEQ;
  const int q0w = qblk * 128 + w * 32;

  // per-(block,wave,lane) base into pre-swizzled pos (shorts)
  const short* pwb = posb + (size_t)h * 1048576 + (size_t)qblk * 131072
                     + w * 2048 + lane * 8;

  __shared__ short kls[3 * 4096];
  __shared__ short vls[3 * 4096];

  // Q as B-operand of 32x32x16: B[k=16kd+8g1+i][col q=c5]; Q pre-scaled.
  bf16x8 qf[4];
#pragma unroll
  for (int kd = 0; kd < 4; ++kd)
    qf[kd] = *(const bf16x8*)(Q + (size_t)(q0w + c5) * 64 + kd * 16 + g1 * 8);

  f32x16 o0, o1;    // O^T: rows d = (r&3)+8*(r>>2)+4g1 (+32 for o1), col q=c5
#pragma unroll
  for (int i = 0; i < 16; ++i) { o0[i] = 0.f; o1[i] = 0.f; }
  float lsum = 0.f;

  // 4-wave STAGE: 2 K + 2 V gload_lds per thread (wave w: rows 8w..8w+7, +32)
  auto STAGE = [&](short* kb_, short* vb_, int kv0) {
    int r0 = w * 8 + (lane >> 3);
    int u0 = (lane & 7) ^ (r0 & 7);
    gload_lds16(K + (size_t)(kv0 + r0) * 64 + u0 * 8, kb_ + w * 512);
    gload_lds16(K + (size_t)(kv0 + 32 + r0) * 64 + u0 * 8, kb_ + 2048 + w * 512);
    gload_lds16(VT + (size_t)r0 * SEQ + kv0 + u0 * 8, vb_ + w * 512);
    gload_lds16(VT + (size_t)(32 + r0) * SEQ + kv0 + u0 * 8, vb_ + 2048 + w * 512);
  };

  short* kbuf0 = kls;        short* vbuf0 = vls;
  short* kbuf1 = kls + 4096; short* vbuf1 = vls + 4096;
  short* kbuf2 = kls + 8192; short* vbuf2 = vls + 8192;

  union pb4 { bf16x8 v; unsigned u[4]; };
  pb4 ua0, ua1, ub0, ub1, na0, na1, nb0, nb1;
  // prologue: pos(0) + stage(0,1)
  ua0.v = *(const bf16x8*)(pwb);
  ua1.v = *(const bf16x8*)(pwb + 512);
  ub0.v = *(const bf16x8*)(pwb + 1024);
  ub1.v = *(const bf16x8*)(pwb + 1536);
  STAGE(kbuf0, vbuf0, 0);
  STAGE(kbuf1, vbuf1, 64);
  asm volatile("s_waitcnt vmcnt(4)" ::: "memory");   // pos(0)+stage(0) landed
  __builtin_amdgcn_sched_barrier(0);
  __builtin_amdgcn_s_barrier();

  for (int ti = 0; ti < 16; ++ti) {
    const int kv0 = ti * 64;

    // distance-1 pos prefetch (consumed next tile; full tile of latency cover)
    if (ti < 15) {
      const short* pnx = pwb + (ti + 1) * 8192;
      na0.v = *(const bf16x8*)(pnx);
      na1.v = *(const bf16x8*)(pnx + 512);
      nb0.v = *(const bf16x8*)(pnx + 1024);
      nb1.v = *(const bf16x8*)(pnx + 1536);
    }
    asm volatile("" ::: "memory");   // pin pos-issue before STAGE
    if (ti < 14) STAGE(kbuf2, vbuf2, kv0 + 128);

    const short* kc = kbuf0;
    const short* vc = vbuf0;

    // QK^T swapped: A = K rows kv (2 blocks of 32), B = Q cols q.
    f32x16 p0, p1;
#pragma unroll
    for (int i = 0; i < 16; ++i) { p0[i] = 0.f; p1[i] = 0.f; }
    __builtin_amdgcn_s_setprio(1);
#pragma unroll
    for (int kd = 0; kd < 4; ++kd) {
      int off0 = (c5 * 128 + kd * 32 + g1 * 16) ^ ((c5 & 7) << 4);
      int off1 = ((32 + c5) * 128 + kd * 32 + g1 * 16) ^ ((c5 & 7) << 4);
      bf16x8 kf0 = *(const bf16x8*)((const char*)kc + off0);
      bf16x8 kf1 = *(const bf16x8*)((const char*)kc + off1);
      p0 = __builtin_amdgcn_mfma_f32_32x32x16_bf16(kf0, qf[kd], p0, 0, 0, 0);
      p1 = __builtin_amdgcn_mfma_f32_32x32x16_bf16(kf1, qf[kd], p1, 0, 0, 0);
    }
    __builtin_amdgcn_s_setprio(0);

    // P = exp2(qk + pos); reg r: kv = (r&3)+8*(r>>2)+4g1 (+32 for p1)
#pragma unroll
    for (int r = 0; r < 16; ++r) {
      unsigned wa = (r < 8) ? ua0.u[(r >> 1) & 3] : ua1.u[(r >> 1) & 3];
      unsigned wb = (r < 8) ? ub0.u[(r >> 1) & 3] : ub1.u[(r >> 1) & 3];
      float a = exp2f(p0[r] + bfsel(wa, r & 1));
      float bq = exp2f(p1[r] + bfsel(wb, r & 1));
      p0[r] = a; p1[r] = bq;
      lsum += a + bq;
    }

    // pack pairs along j: pk[2m+p] = (kv=8m+4g1+2p, +1)
    unsigned pk0[8], pk1[8];
#pragma unroll
    for (int m = 0; m < 4; ++m) {
      pk0[2 * m]     = cvtpk(p0[4 * m],     p0[4 * m + 1]);
      pk0[2 * m + 1] = cvtpk(p0[4 * m + 2], p0[4 * m + 3]);
      pk1[2 * m]     = cvtpk(p1[4 * m],     p1[4 * m + 1]);
      pk1[2 * m + 1] = cvtpk(p1[4 * m + 2], p1[4 * m + 3]);
    }

    // PV B-frags: step s covers kv 16s..16s+15; k = 8g1+i
    union bb { bf16x8 v; unsigned u[4]; } B0, B1, B2, B3;
    MKFRAG(B0, pk0[0], pk0[1], pk0[2], pk0[3]);   // s=0
    MKFRAG(B1, pk0[4], pk0[5], pk0[6], pk0[7]);   // s=1
    MKFRAG(B2, pk1[0], pk1[1], pk1[2], pk1[3]);   // s=2
    MKFRAG(B3, pk1[4], pk1[5], pk1[6], pk1[7]);   // s=3

    // PV: O^T += V^T (A, rows d) x P^T (B, cols q)
    __builtin_amdgcn_s_setprio(1);
#define PVSTEP(Bv, s)                                                        \
    { int o0f = (c5 * 128 + (s) * 32 + g1 * 16) ^ ((c5 & 7) << 4);           \
      int o1f = ((32 + c5) * 128 + (s) * 32 + g1 * 16) ^ ((c5 & 7) << 4);    \
      bf16x8 vf0 = *(const bf16x8*)((const char*)vc + o0f);                  \
      bf16x8 vf1 = *(const bf16x8*)((const char*)vc + o1f);                  \
      o0 = __builtin_amdgcn_mfma_f32_32x32x16_bf16(vf0, Bv.v, o0, 0, 0, 0);  \
      o1 = __builtin_amdgcn_mfma_f32_32x32x16_bf16(vf1, Bv.v, o1, 0, 0, 0); }
    PVSTEP(B0, 0); PVSTEP(B1, 1); PVSTEP(B2, 2); PVSTEP(B3, 3);
#undef PVSTEP
    __builtin_amdgcn_s_setprio(0);

    // rotate pos regs and LDS buffers
    if (ti < 15) { ua0 = na0; ua1 = na1; ub0 = nb0; ub1 = nb1; }
    short* tk = kbuf0; kbuf0 = kbuf1; kbuf1 = kbuf2; kbuf2 = tk;
    short* tv = vbuf0; vbuf0 = vbuf1; vbuf1 = vbuf2; vbuf2 = tv;

    // pos(ti+1) landed via the register copies; stage(ti+2)[4] may remain.
    if (ti < 15) {
      if (ti < 14) asm volatile("s_waitcnt vmcnt(4)" ::: "memory");
      else         asm volatile("s_waitcnt vmcnt(0)" ::: "memory");
      __builtin_amdgcn_sched_barrier(0);
      __builtin_amdgcn_s_barrier();
    }
  }

  // lane and lane^32 hold complementary kv rows of the same q-column
  lsum += __shfl_xor(lsum, 32);
  float inv = 1.0f / lsum;
  size_t obase = (size_t)(b * SEQ + q0w + c5) * 768 + h * 64 + g1 * 4;
#pragma unroll
  for (int m = 0; m < 4; ++m) {
    short4v ov0, ov1;
#pragma unroll
    for (int j = 0; j < 4; ++j) {
      ov0[j] = (short)f2bf(o0[4 * m + j] * inv);
      ov1[j] = (short)f2bf(o1[4 * m + j] * inv);
    }
    *(short4v*)(outb + obase + m * 8) = ov0;
    *(short4v*)(outb + obase + 32 + m * 8) = ov1;
  }
}

extern "C" void kernel_launch(void* const* d_in, const int* in_sizes, int n_in,
                              void* d_out, int out_size, void* d_ws, size_t ws_size,
                              hipStream_t stream) {
  const float* x      = (const float*)d_in[0];
  const float* pos    = (const float*)d_in[1];
  const float* W_qkv  = (const float*)d_in[2];
  const float* b_qkv  = (const float*)d_in[3];
  const float* W_proj = (const float*)d_in[4];
  const float* b_proj = (const float*)d_in[5];
  float* out = (float*)d_out;

  char* ws = (char*)d_ws;
  short* A       = (short*)(ws);                  // 12,582,912 (consumed by gemm<1>)
  short* attnbuf = (short*)(ws);                  // alias of A (written after)
  short* Bt      = (short*)(ws + 12582912);       //  3,538,944
  short* wpt     = (short*)(ws + 16121856);       //  1,179,648
  short* qbuf    = (short*)(ws + 17301504);       // 12,582,912
  short* kbuf    = (short*)(ws + 29884416);       // 12,582,912
  short* vtbuf   = (short*)(ws + 42467328);       // 12,582,912
  short* posb    = (short*)(ws + 55050240);       // 25,165,824
  // total: 80,216,064 bytes

  prep_all_kernel<<<12864, 256, 0, stream>>>(x, A, W_qkv, Bt, W_proj, wpt,
                                             pos, posb);
  gemm_kernel<1><<<1152, 512, 0, stream>>>(A, Bt, b_qkv,
                                           qbuf, kbuf, vtbuf, nullptr);
  attn_kernel<<<768, 256, 0, stream>>>(qbuf, kbuf, vtbuf, posb, attnbuf);
  gemm_kernel<2><<<384, 512, 0, stream>>>(attnbuf, wpt, b_proj,
                                          nullptr, nullptr, nullptr, out);
}

// Round 18
// 139.862 us; speedup vs baseline: 1.0601x; 1.0601x over previous
//
#include <hip/hip_runtime.h>

#define SEQ   1024
#define HEADS 12
#define CDIM  768
#define BATCH 8

// 0.125 * log2(e): folds the 1/sqrt(64) score scale and the exp->exp2 change
#define QSCALE 0.18033688011112042f

typedef __attribute__((ext_vector_type(8))) short bf16x8;
typedef __attribute__((ext_vector_type(4))) float f32x4;
typedef __attribute__((ext_vector_type(16))) float f32x16;
typedef __attribute__((ext_vector_type(4))) float float4v;
typedef __attribute__((ext_vector_type(4))) short short4v;

__device__ __forceinline__ void gload_lds16(const void* g, void* l) {
  __builtin_amdgcn_global_load_lds(
      (const __attribute__((address_space(1))) unsigned int*)g,
      (__attribute__((address_space(3))) unsigned int*)l, 16, 0, 0);
}

__device__ __forceinline__ unsigned short f2bf(float f) {
  union { float f; unsigned u; } v; v.f = f;
  unsigned r = v.u + 0x7fff + ((v.u >> 16) & 1);
  return (unsigned short)(r >> 16);
}

// pack two f32 -> u32 of 2x bf16 (lo = a, hi = b); no builtin on gfx950
__device__ __forceinline__ unsigned cvtpk(float a, float b) {
  unsigned r;
  asm("v_cvt_pk_bf16_f32 %0, %1, %2" : "=v"(r) : "v"(a), "v"(b));
  return r;
}

// select bf16 half of a packed u32 as f32 (odd -> high half, even -> low)
__device__ __forceinline__ float bfsel(unsigned u, int odd) {
  union { unsigned u; float f; } v;
  v.u = odd ? (u & 0xffff0000u) : (u << 16);
  return v.f;
}

// one pos->posb job: job index j in [0, 1572864)
__device__ __forceinline__ void pos_job(const float* __restrict__ P,
                                        short* __restrict__ PB, int j) {
  int ln = j & 63, jh = (j >> 6) & 1, i0 = (j >> 7) & 1, w4 = (j >> 8) & 3,
      ti = (j >> 10) & 15, qb = (j >> 14) & 7, hh = j >> 17;
  int q = qb * 128 + w4 * 32 + (ln & 31);
  const float* src = P + ((size_t)hh * SEQ + q) * SEQ + ti * 64 + i0 * 32
                     + 4 * (ln >> 5) + 16 * jh;
  float4v v0 = *(const float4v*)(src);       // jl = 0..3
  float4v v1 = *(const float4v*)(src + 8);   // jl = 4..7
  union { short s[8]; bf16x8 v; } o;
#pragma unroll
  for (int p = 0; p < 4; ++p) {
    o.s[p]     = (short)f2bf(v0[p] * QSCALE);
    o.s[4 + p] = (short)f2bf(v1[p] * QSCALE);
  }
  *(bf16x8*)(PB + (size_t)j * 8) = o.v;
}

// Merged prep: blocks [0,6144) = x->bf16; [6144,6576) = W_qkv transpose;
// [6576,6720) = W_proj transpose.
__global__ __launch_bounds__(256) void prep_all_kernel(
    const float* __restrict__ x, short* __restrict__ A,
    const float* __restrict__ Wqkv, short* __restrict__ Bt,
    const float* __restrict__ Wproj, short* __restrict__ wpt) {
  __shared__ float tile[64][65];
  const int bid = blockIdx.x;
  const int t = threadIdx.x;
  if (bid < 6144) {
    int i = bid * 256 + t;
    int r = i / 192;
    int c4 = (i % 192) * 4;
    float4v xv = *(const float4v*)(x + (size_t)r * 768 + c4);
    short4v hi;
#pragma unroll
    for (int j = 0; j < 4; ++j) hi[j] = (short)f2bf(xv[j]);
    *(short4v*)(A + (size_t)r * 768 + c4) = hi;
  } else if (bid < 6576) {
    int idx = bid - 6144;
    int k0 = (idx % 12) * 64;
    int n0 = (idx / 12) * 64;
#pragma unroll
    for (int it = 0; it < 16; ++it) {
      int r = it * 4 + (t >> 6);
      int c = t & 63;
      tile[r][c] = Wqkv[(size_t)(k0 + r) * 2304 + n0 + c];
    }
    __syncthreads();
#pragma unroll
    for (int it = 0; it < 16; ++it) {
      int nr = it * 4 + (t >> 6);
      int kc = t & 63;
      Bt[(size_t)(n0 + nr) * 768 + k0 + kc] = (short)f2bf(tile[kc][nr]);
    }
  } else {
    int idx = bid - 6576;
    int k0 = (idx % 12) * 64;
    int n0 = (idx / 12) * 64;
#pragma unroll
    for (int it = 0; it < 16; ++it) {
      int r = it * 4 + (t >> 6);
      int c = t & 63;
      tile[r][c] = Wproj[(size_t)(k0 + r) * 768 + n0 + c];
    }
    __syncthreads();
#pragma unroll
    for (int it = 0; it < 16; ++it) {
      int nr = it * 4 + (t >> 6);
      int kc = t & 63;
      wpt[(size_t)(n0 + nr) * 768 + k0 + kc] = (short)f2bf(tile[kc][nr]);
    }
  }
}

// Shared 128x128-tile GEMM, BK=64, K=768, 8 waves (2x4), 16x16x32 bf16 MFMA.
// 2-phase issue-early pipeline; XCD-chunked linear grid (gemm bids 0..NWG-1
// unchanged). MODE 1 grid additionally carries 768 APPENDED pos-conversion
// blocks (bids >= 1152): independent streaming blocks that backfill the idle
// CUs of gemm1's 128-block tail round (co-resident overlap, m114 mechanism;
// the gemm inner loop is untouched -- unlike the failed same-block fusion).
template <int MODE>
__global__ __launch_bounds__(512, 4) void gemm_kernel(
    const short* __restrict__ A, const short* __restrict__ Bt,
    const float* __restrict__ bias,
    short* __restrict__ outQ, short* __restrict__ outK, short* __restrict__ outVT,
    float* __restrict__ outF,
    const float* __restrict__ pos, short* __restrict__ posb) {
  constexpr int NBLK = (MODE == 1) ? 18 : 6;     // n-blocks per m-row
  constexpr int CHUNK = (MODE == 1) ? 144 : 48;  // nwg/8 (both divisible)
  constexpr int NWG = (MODE == 1) ? 1152 : 384;
  const int bid = blockIdx.x;
  if (MODE == 1 && bid >= NWG) {
    // appended pos-conversion block: 4 jobs/thread, 768 blocks x 512 threads
    const int base = (bid - NWG) * 512 + threadIdx.x;
#pragma unroll
    for (int s = 0; s < 4; ++s) pos_job(pos, posb, base + s * 393216);
    return;
  }
  const int lb = (bid & 7) * CHUNK + (bid >> 3); // XCD-chunked, bijective
  const int n0 = (lb % NBLK) * 128;
  const int m0 = (lb / NBLK) * 128;

  __shared__ short Als[2][128 * 64];
  __shared__ short Bls[2][128 * 64];
  const int tid = threadIdx.x;
  const int lane = tid & 63;
  const int w = tid >> 6;
  const int wr = (w & 1) * 64;       // 2 row-groups of 64
  const int wc = (w >> 1) * 32;      // 4 col-groups of 32
  f32x4 acc[4][2];
#pragma unroll
  for (int mi = 0; mi < 4; ++mi)
#pragma unroll
    for (int ni = 0; ni < 2; ++ni) acc[mi][ni] = (f32x4){0.f, 0.f, 0.f, 0.f};

  auto STAGE = [&](int buf, int k0) {
#pragma unroll
    for (int pass = 0; pass < 2; ++pass) {
      int rbase = pass * 64 + w * 8;
      int row = rbase + (lane >> 3);
      int ul = (lane & 7) ^ (row & 7);
      gload_lds16(A + (size_t)(m0 + row) * 768 + k0 + ul * 8, Als[buf] + rbase * 64);
      gload_lds16(Bt + (size_t)(n0 + row) * 768 + k0 + ul * 8, Bls[buf] + rbase * 64);
    }
  };

  STAGE(0, 0);
  asm volatile("s_waitcnt vmcnt(0)" ::: "memory");
  __builtin_amdgcn_sched_barrier(0);
  __builtin_amdgcn_s_barrier();

  for (int t = 0; t < 12; ++t) {
    if (t < 11) STAGE((t + 1) & 1, (t + 1) * 64);   // loads fly during compute
    const short* Ab = Als[t & 1];
    const short* Bb = Bls[t & 1];
    __builtin_amdgcn_s_setprio(1);
#pragma unroll
    for (int kk = 0; kk < 2; ++kk) {
      bf16x8 af[4], bfv[2];
#pragma unroll
      for (int mi = 0; mi < 4; ++mi) {
        int row = wr + mi * 16 + (lane & 15);
        int off = (row * 128 + kk * 64 + (lane >> 4) * 16) ^ ((row & 7) << 4);
        af[mi] = *(const bf16x8*)((const char*)Ab + off);
      }
#pragma unroll
      for (int ni = 0; ni < 2; ++ni) {
        int row = wc + ni * 16 + (lane & 15);
        int off = (row * 128 + kk * 64 + (lane >> 4) * 16) ^ ((row & 7) << 4);
        bfv[ni] = *(const bf16x8*)((const char*)Bb + off);
      }
#pragma unroll
      for (int mi = 0; mi < 4; ++mi)
#pragma unroll
        for (int ni = 0; ni < 2; ++ni)
          acc[mi][ni] = __builtin_amdgcn_mfma_f32_16x16x32_bf16(
              af[mi], bfv[ni], acc[mi][ni], 0, 0, 0);
    }
    __builtin_amdgcn_s_setprio(0);
    if (t < 11) {
      // own stage(t+1) proven landed before the publishing barrier
      asm volatile("s_waitcnt vmcnt(0)" ::: "memory");
      __builtin_amdgcn_sched_barrier(0);
      __builtin_amdgcn_s_barrier();
    }
  }

  if (MODE == 1) {
    // block-uniform third: n0 multiple of 128, 128 | 768
    const int three = n0 / 768;
    const int nb = n0 - three * 768;
#pragma unroll
    for (int mi = 0; mi < 4; ++mi)
#pragma unroll
      for (int ni = 0; ni < 2; ++ni)
#pragma unroll
        for (int j = 0; j < 4; ++j) {
          int row = m0 + wr + mi * 16 + ((lane >> 4) << 2) + j;
          int col = n0 + wc + ni * 16 + (lane & 15);
          float v = acc[mi][ni][j] + bias[col];
          int rem = nb + wc + ni * 16 + (lane & 15);
          int hh = rem >> 6, d = rem & 63;
          int b = row >> 10, n = row & 1023;
          size_t bh = (size_t)(b * 12 + hh);
          if (three == 0)      outQ[(bh * 1024 + n) * 64 + d] = (short)f2bf(v * QSCALE);
          else if (three == 1) outK[(bh * 1024 + n) * 64 + d] = (short)f2bf(v);
          else                 outVT[(bh * 64 + d) * 1024 + n] = (short)f2bf(v);
        }
  } else {
#pragma unroll
    for (int mi = 0; mi < 4; ++mi)
#pragma unroll
      for (int ni = 0; ni < 2; ++ni)
#pragma unroll
        for (int j = 0; j < 4; ++j) {
          int row = m0 + wr + mi * 16 + ((lane >> 4) << 2) + j;
          int col = n0 + wc + ni * 16 + (lane & 15);
          outF[(size_t)row * 768 + col] = acc[mi][ni][j] + bias[col];
        }
  }
}

// build one PV B-frag (4 u32 = 8 bf16, k = kv) from packed P pairs:
// permlane32_swap(x=pk[m][p], y=pk[m+1][p]) -> x' = frag reg (own|swap),
// y' = frag reg (swap|own) for the two lane halves. 4 swaps per 32-kv block.
#define MKFRAG(B, pA, pB, pC, pD)                                    \
  { unsigned x0 = (pA), y0 = (pC), x1 = (pB), y1 = (pD);             \
    asm("v_permlane32_swap_b32 %0, %1" : "+v"(x0), "+v"(y0));        \
    asm("v_permlane32_swap_b32 %0, %1" : "+v"(x1), "+v"(y1));        \
    B.u[0] = x0; B.u[1] = x1; B.u[2] = y0; B.u[3] = y1; }

// Flash attention, 32x32x16 MFMA, swapped QK^T, fixed-shift softmax,
// permlane32_swap P-redistribute, distance-2 KV pipeline, coalesced
// pre-swizzled bf16 pos (QSCALE folded) prefetched at distance 1,
// h-major XCD swizzle. grid: 768 blocks x 256 threads; 4 waves x 32 q-rows.
__global__ __launch_bounds__(256, 3) void attn_kernel(
    const short* __restrict__ qb, const short* __restrict__ kb,
    const short* __restrict__ vtb, const short* __restrict__ posb,
    short* __restrict__ outb) {
  // h-major XCD swizzle: the 8 same-(h,qblk) diff-b blocks share one XCD L2.
  const int bid = blockIdx.x;
  const int lb = (bid & 7) * 96 + (bid >> 3);
  const int qblk = lb & 7;
  const int hb = lb >> 3;            // 0..95 = h*8 + b
  const int h = hb >> 3, b = hb & 7;

  const int tid = threadIdx.x, lane = tid & 63, w = tid >> 6;
  const int c5 = lane & 31, g1 = lane >> 5;
  const size_t bh = (size_t)(b * 12 + h);
  const short* Q = qb + bh * SEQ * 64;
  const short* K = kb + bh * SEQ * 64;
  const short* VT = vtb + bh * 64 * SEQ;
  const int q0w = qblk * 128 + w * 32;

  // per-(block,wave,lane) base into pre-swizzled pos (shorts)
  const short* pwb = posb + (size_t)h * 1048576 + (size_t)qblk * 131072
                     + w * 2048 + lane * 8;

  __shared__ short kls[3 * 4096];
  __shared__ short vls[3 * 4096];

  // Q as B-operand of 32x32x16: B[k=16kd+8g1+i][col q=c5]; Q pre-scaled.
  bf16x8 qf[4];
#pragma unroll
  for (int kd = 0; kd < 4; ++kd)
    qf[kd] = *(const bf16x8*)(Q + (size_t)(q0w + c5) * 64 + kd * 16 + g1 * 8);

  f32x16 o0, o1;    // O^T: rows d = (r&3)+8*(r>>2)+4g1 (+32 for o1), col q=c5
#pragma unroll
  for (int i = 0; i < 16; ++i) { o0[i] = 0.f; o1[i] = 0.f; }
  float lsum = 0.f;

  // 4-wave STAGE: 2 K + 2 V gload_lds per thread (wave w: rows 8w..8w+7, +32)
  auto STAGE = [&](short* kb_, short* vb_, int kv0) {
    int r0 = w * 8 + (lane >> 3);
    int u0 = (lane & 7) ^ (r0 & 7);
    gload_lds16(K + (size_t)(kv0 + r0) * 64 + u0 * 8, kb_ + w * 512);
    gload_lds16(K + (size_t)(kv0 + 32 + r0) * 64 + u0 * 8, kb_ + 2048 + w * 512);
    gload_lds16(VT + (size_t)r0 * SEQ + kv0 + u0 * 8, vb_ + w * 512);
    gload_lds16(VT + (size_t)(32 + r0) * SEQ + kv0 + u0 * 8, vb_ + 2048 + w * 512);
  };

  short* kbuf0 = kls;        short* vbuf0 = vls;
  short* kbuf1 = kls + 4096; short* vbuf1 = vls + 4096;
  short* kbuf2 = kls + 8192; short* vbuf2 = vls + 8192;

  union pb4 { bf16x8 v; unsigned u[4]; };
  pb4 ua0, ua1, ub0, ub1, na0, na1, nb0, nb1;
  // prologue: pos(0) + stage(0,1)
  ua0.v = *(const bf16x8*)(pwb);
  ua1.v = *(const bf16x8*)(pwb + 512);
  ub0.v = *(const bf16x8*)(pwb + 1024);
  ub1.v = *(const bf16x8*)(pwb + 1536);
  STAGE(kbuf0, vbuf0, 0);
  STAGE(kbuf1, vbuf1, 64);
  asm volatile("s_waitcnt vmcnt(4)" ::: "memory");   // pos(0)+stage(0) landed
  __builtin_amdgcn_sched_barrier(0);
  __builtin_amdgcn_s_barrier();

  for (int ti = 0; ti < 16; ++ti) {
    const int kv0 = ti * 64;

    // distance-1 pos prefetch (consumed next tile; full tile of latency cover)
    if (ti < 15) {
      const short* pnx = pwb + (ti + 1) * 8192;
      na0.v = *(const bf16x8*)(pnx);
      na1.v = *(const bf16x8*)(pnx + 512);
      nb0.v = *(const bf16x8*)(pnx + 1024);
      nb1.v = *(const bf16x8*)(pnx + 1536);
    }
    asm volatile("" ::: "memory");   // pin pos-issue before STAGE
    if (ti < 14) STAGE(kbuf2, vbuf2, kv0 + 128);

    const short* kc = kbuf0;
    const short* vc = vbuf0;

    // QK^T swapped: A = K rows kv (2 blocks of 32), B = Q cols q.
    f32x16 p0, p1;
#pragma unroll
    for (int i = 0; i < 16; ++i) { p0[i] = 0.f; p1[i] = 0.f; }
    __builtin_amdgcn_s_setprio(1);
#pragma unroll
    for (int kd = 0; kd < 4; ++kd) {
      int off0 = (c5 * 128 + kd * 32 + g1 * 16) ^ ((c5 & 7) << 4);
      int off1 = ((32 + c5) * 128 + kd * 32 + g1 * 16) ^ ((c5 & 7) << 4);
      bf16x8 kf0 = *(const bf16x8*)((const char*)kc + off0);
      bf16x8 kf1 = *(const bf16x8*)((const char*)kc + off1);
      p0 = __builtin_amdgcn_mfma_f32_32x32x16_bf16(kf0, qf[kd], p0, 0, 0, 0);
      p1 = __builtin_amdgcn_mfma_f32_32x32x16_bf16(kf1, qf[kd], p1, 0, 0, 0);
    }
    __builtin_amdgcn_s_setprio(0);

    // P = exp2(qk + pos); reg r: kv = (r&3)+8*(r>>2)+4g1 (+32 for p1)
#pragma unroll
    for (int r = 0; r < 16; ++r) {
      unsigned wa = (r < 8) ? ua0.u[(r >> 1) & 3] : ua1.u[(r >> 1) & 3];
      unsigned wb = (r < 8) ? ub0.u[(r >> 1) & 3] : ub1.u[(r >> 1) & 3];
      float a = exp2f(p0[r] + bfsel(wa, r & 1));
      float bq = exp2f(p1[r] + bfsel(wb, r & 1));
      p0[r] = a; p1[r] = bq;
      lsum += a + bq;
    }

    // pack pairs along j: pk[2m+p] = (kv=8m+4g1+2p, +1)
    unsigned pk0[8], pk1[8];
#pragma unroll
    for (int m = 0; m < 4; ++m) {
      pk0[2 * m]     = cvtpk(p0[4 * m],     p0[4 * m + 1]);
      pk0[2 * m + 1] = cvtpk(p0[4 * m + 2], p0[4 * m + 3]);
      pk1[2 * m]     = cvtpk(p1[4 * m],     p1[4 * m + 1]);
      pk1[2 * m + 1] = cvtpk(p1[4 * m + 2], p1[4 * m + 3]);
    }

    // PV B-frags: step s covers kv 16s..16s+15; k = 8g1+i
    union bb { bf16x8 v; unsigned u[4]; } B0, B1, B2, B3;
    MKFRAG(B0, pk0[0], pk0[1], pk0[2], pk0[3]);   // s=0
    MKFRAG(B1, pk0[4], pk0[5], pk0[6], pk0[7]);   // s=1
    MKFRAG(B2, pk1[0], pk1[1], pk1[2], pk1[3]);   // s=2
    MKFRAG(B3, pk1[4], pk1[5], pk1[6], pk1[7]);   // s=3

    // PV: O^T += V^T (A, rows d) x P^T (B, cols q)
    __builtin_amdgcn_s_setprio(1);
#define PVSTEP(Bv, s)                                                        \
    { int o0f = (c5 * 128 + (s) * 32 + g1 * 16) ^ ((c5 & 7) << 4);           \
      int o1f = ((32 + c5) * 128 + (s) * 32 + g1 * 16) ^ ((c5 & 7) << 4);    \
      bf16x8 vf0 = *(const bf16x8*)((const char*)vc + o0f);                  \
      bf16x8 vf1 = *(const bf16x8*)((const char*)vc + o1f);                  \
      o0 = __builtin_amdgcn_mfma_f32_32x32x16_bf16(vf0, Bv.v, o0, 0, 0, 0);  \
      o1 = __builtin_amdgcn_mfma_f32_32x32x16_bf16(vf1, Bv.v, o1, 0, 0, 0); }
    PVSTEP(B0, 0); PVSTEP(B1, 1); PVSTEP(B2, 2); PVSTEP(B3, 3);
#undef PVSTEP
    __builtin_amdgcn_s_setprio(0);

    // rotate pos regs and LDS buffers
    if (ti < 15) { ua0 = na0; ua1 = na1; ub0 = nb0; ub1 = nb1; }
    short* tk = kbuf0; kbuf0 = kbuf1; kbuf1 = kbuf2; kbuf2 = tk;
    short* tv = vbuf0; vbuf0 = vbuf1; vbuf1 = vbuf2; vbuf2 = tv;

    // pos(ti+1) landed via the register copies; stage(ti+2)[4] may remain.
    if (ti < 15) {
      if (ti < 14) asm volatile("s_waitcnt vmcnt(4)" ::: "memory");
      else         asm volatile("s_waitcnt vmcnt(0)" ::: "memory");
      __builtin_amdgcn_sched_barrier(0);
      __builtin_amdgcn_s_barrier();
    }
  }

  // lane and lane^32 hold complementary kv rows of the same q-column
  lsum += __shfl_xor(lsum, 32);
  float inv = 1.0f / lsum;
  size_t obase = (size_t)(b * SEQ + q0w + c5) * 768 + h * 64 + g1 * 4;
#pragma unroll
  for (int m = 0; m < 4; ++m) {
    short4v ov0, ov1;
#pragma unroll
    for (int j = 0; j < 4; ++j) {
      ov0[j] = (short)f2bf(o0[4 * m + j] * inv);
      ov1[j] = (short)f2bf(o1[4 * m + j] * inv);
    }
    *(short4v*)(outb + obase + m * 8) = ov0;
    *(short4v*)(outb + obase + 32 + m * 8) = ov1;
  }
}

extern "C" void kernel_launch(void* const* d_in, const int* in_sizes, int n_in,
                              void* d_out, int out_size, void* d_ws, size_t ws_size,
                              hipStream_t stream) {
  const float* x      = (const float*)d_in[0];
  const float* pos    = (const float*)d_in[1];
  const float* W_qkv  = (const float*)d_in[2];
  const float* b_qkv  = (const float*)d_in[3];
  const float* W_proj = (const float*)d_in[4];
  const float* b_proj = (const float*)d_in[5];
  float* out = (float*)d_out;

  char* ws = (char*)d_ws;
  short* A       = (short*)(ws);                  // 12,582,912 (consumed by gemm<1>)
  short* attnbuf = (short*)(ws);                  // alias of A (written after)
  short* Bt      = (short*)(ws + 12582912);       //  3,538,944
  short* wpt     = (short*)(ws + 16121856);       //  1,179,648
  short* qbuf    = (short*)(ws + 17301504);       // 12,582,912
  short* kbuf    = (short*)(ws + 29884416);       // 12,582,912
  short* vtbuf   = (short*)(ws + 42467328);       // 12,582,912
  short* posb    = (short*)(ws + 55050240);       // 25,165,824
  // total: 80,216,064 bytes

  prep_all_kernel<<<6720, 256, 0, stream>>>(x, A, W_qkv, Bt, W_proj, wpt);
  // 1152 GEMM blocks + 768 appended pos-conversion blocks (tail overlap)
  gemm_kernel<1><<<1920, 512, 0, stream>>>(A, Bt, b_qkv,
                                           qbuf, kbuf, vtbuf, nullptr,
                                           pos, posb);
  attn_kernel<<<768, 256, 0, stream>>>(qbuf, kbuf, vtbuf, posb, attnbuf);
  gemm_kernel<2><<<384, 512, 0, stream>>>(attnbuf, wpt, b_proj,
                                          nullptr, nullptr, nullptr, out,
                                          nullptr, nullptr);
}